// Round 6
// baseline (83.184 us; speedup 1.0000x reference)
//
#include <hip/hip_runtime.h>
#include <hip/hip_bf16.h>

constexpr int B_  = 8;
constexpr int S_  = 512;
constexpr int V_  = 30522;
constexpr int V2_ = V_ / 2;                      // 15261 float2 per row
constexpr int V4_ = V_ / 4;                      // 7630 full float4 per row (+1 float2 tail)

// ---------------- Kernel 1: masked partial max-pool, float4 row-streaming ---------
// Block (vs, g, b) streams contiguous ~30.5 KB float4 slices of every active row in
// group g (compacted rows g, g+NS, ...), running max in registers.
constexpr int K1_THREADS = 1024;
constexpr int VSPLIT  = 4;
constexpr int SLICE4  = 1908;                    // float4 per slice (slice 3: 1906 + tail)
constexpr int NS      = 16;                      // row groups -> 512 blocks total
constexpr int NSLOT   = 2;                       // 2 float4 per thread (2048 slots >= 1908)

__global__ __launch_bounds__(K1_THREADS)
void splade_partial_max(const float* __restrict__ logits,
                        const int* __restrict__ mask,
                        float* __restrict__ partial)     // [NS][B][V_] in ws
{
    __shared__ int s_idx[S_];
    __shared__ int s_cnt;
    const int vs = blockIdx.x;
    const int g  = blockIdx.y;
    const int b  = blockIdx.z;

    // Wave 0 compacts active row indices via ballot prefix (no LDS atomics).
    if (threadIdx.x < 64) {
        const int lane = threadIdx.x;
        int cnt = 0;
        for (int base = 0; base < S_; base += 64) {
            const int m = mask[b * S_ + base + lane] != 0;
            const unsigned long long bal = __ballot(m);
            if (m) s_idx[cnt + (int)__popcll(bal & ((1ull << lane) - 1ull))] = base + lane;
            cnt += (int)__popcll(bal);
        }
        if (lane == 0) s_cnt = cnt;
    }
    __syncthreads();
    const int n = s_cnt;

    // Per-slot float4 column index within the row. Invalid slots clamp to col 0
    // (single broadcast cache line -> negligible) and are skipped on store.
    const int len4 = (vs == VSPLIT - 1) ? (V4_ - vs * SLICE4) : SLICE4;  // 1908 / 1906
    int  col4[NSLOT];
    bool valid[NSLOT];
#pragma unroll
    for (int p = 0; p < NSLOT; ++p) {
        const int idx4 = threadIdx.x + p * K1_THREADS;
        valid[p] = (idx4 < len4);
        col4[p]  = valid[p] ? (vs * SLICE4 + idx4) : 0;
    }

    float4 acc[NSLOT];
#pragma unroll
    for (int p = 0; p < NSLOT; ++p) acc[p] = make_float4(0.f, 0.f, 0.f, 0.f);

    // One thread in the last slice owns the per-row trailing float2 (V % 4 == 2).
    const bool do_tail = (vs == VSPLIT - 1) && (threadIdx.x == 0);
    float2 acc_t = make_float2(0.f, 0.f);

    int r = g;
    for (; r + NS < n; r += 2 * NS) {                    // 2-row pipeline
        const int s0 = s_idx[r], s1 = s_idx[r + NS];
        const float* r0 = logits + (size_t)(b * S_ + s0) * V_;
        const float* r1 = logits + (size_t)(b * S_ + s1) * V_;
        float4 x0[NSLOT], x1[NSLOT];
#pragma unroll
        for (int p = 0; p < NSLOT; ++p)
            x0[p] = *reinterpret_cast<const float4*>(r0 + 4 * col4[p]);
#pragma unroll
        for (int p = 0; p < NSLOT; ++p)
            x1[p] = *reinterpret_cast<const float4*>(r1 + 4 * col4[p]);
        if (do_tail) {
            const float2 t0 = *reinterpret_cast<const float2*>(r0 + 2 * (V2_ - 1));
            const float2 t1 = *reinterpret_cast<const float2*>(r1 + 2 * (V2_ - 1));
            acc_t.x = fmaxf(acc_t.x, fmaxf(t0.x, t1.x));
            acc_t.y = fmaxf(acc_t.y, fmaxf(t0.y, t1.y));
        }
#pragma unroll
        for (int p = 0; p < NSLOT; ++p) {
            acc[p].x = fmaxf(acc[p].x, fmaxf(x0[p].x, x1[p].x));
            acc[p].y = fmaxf(acc[p].y, fmaxf(x0[p].y, x1[p].y));
            acc[p].z = fmaxf(acc[p].z, fmaxf(x0[p].z, x1[p].z));
            acc[p].w = fmaxf(acc[p].w, fmaxf(x0[p].w, x1[p].w));
        }
    }
    if (r < n) {                                         // odd tail row
        const float* r0 = logits + (size_t)(b * S_ + s_idx[r]) * V_;
        float4 x0[NSLOT];
#pragma unroll
        for (int p = 0; p < NSLOT; ++p)
            x0[p] = *reinterpret_cast<const float4*>(r0 + 4 * col4[p]);
        if (do_tail) {
            const float2 t0 = *reinterpret_cast<const float2*>(r0 + 2 * (V2_ - 1));
            acc_t.x = fmaxf(acc_t.x, t0.x);
            acc_t.y = fmaxf(acc_t.y, t0.y);
        }
#pragma unroll
        for (int p = 0; p < NSLOT; ++p) {
            acc[p].x = fmaxf(acc[p].x, x0[p].x);
            acc[p].y = fmaxf(acc[p].y, x0[p].y);
            acc[p].z = fmaxf(acc[p].z, x0[p].z);
            acc[p].w = fmaxf(acc[p].w, x0[p].w);
        }
    }

    float* dst = partial + ((size_t)g * B_ + b) * V_;
#pragma unroll
    for (int p = 0; p < NSLOT; ++p)
        if (valid[p])
            *reinterpret_cast<float4*>(dst + 4 * col4[p]) = acc[p];
    if (do_tail)
        *reinterpret_cast<float2*>(dst + 2 * (V2_ - 1)) = acc_t;
}

// ---------------- Kernel M: WIDE merge of NS partials -> out ----------------
// 480 blocks; k2 must never read the 15.6 MB of partials (8-CU bandwidth trap).
constexpr int KM_THREADS  = 256;
constexpr int KM_BLOCKS_X = (V2_ + KM_THREADS - 1) / KM_THREADS;   // 60

__global__ __launch_bounds__(KM_THREADS)
void splade_merge(const float* __restrict__ partial, float* __restrict__ out)
{
    const int b    = blockIdx.y;
    const int idx2 = blockIdx.x * KM_THREADS + threadIdx.x;
    if (idx2 >= V2_) return;
    const float2* p0 = reinterpret_cast<const float2*>(partial) + (size_t)b * V2_ + idx2;
    float2 m = make_float2(0.0f, 0.0f);
#pragma unroll
    for (int gg = 0; gg < NS; ++gg) {
        const float2 x = p0[(size_t)gg * B_ * V2_];
        m.x = fmaxf(m.x, x.x);
        m.y = fmaxf(m.y, x.y);
    }
    reinterpret_cast<float2*>(out)[(size_t)b * V2_ + idx2] = m;
}

// ---------------- Kernel 2: per-row exact top-k threshold + finalize ----------------
// One 1024-thread block per batch row; reads ONLY the final 1 MB (float2 loads).
// k-th largest (ties counted, = top_values[...,-1]) via binary search on the uint
// bit pattern; ballot+popc counts, one barrier per step.
constexpr int K2_BLOCK = 1024;
constexpr int NPT2 = (V2_ + K2_BLOCK - 1) / K2_BLOCK;    // 15 float2 -> 30 uints

__global__ __launch_bounds__(K2_BLOCK)
void splade_topk_kernel(float* __restrict__ out,
                        const int* __restrict__ topk_ptr)
{
    const int b = blockIdx.x;
    const int k = topk_ptr[0];
    float2* row2 = reinterpret_cast<float2*>(out) + (size_t)b * V2_;

    unsigned int v[2 * NPT2];            // register cache, static indexing only
#pragma unroll
    for (int i = 0; i < NPT2; ++i) {
        const int idx2 = threadIdx.x + i * K2_BLOCK;
        float2 x = make_float2(0.0f, 0.0f);              // OOB zeros never counted
        if (idx2 < V2_) x = row2[idx2];
        v[2 * i]     = __float_as_uint(x.x);
        v[2 * i + 1] = __float_as_uint(x.y);
    }

    __shared__ int s_cnt[32];
    for (int i = threadIdx.x; i < 32; i += K2_BLOCK) s_cnt[i] = 0;
    __syncthreads();

    // invariant: count(bits >= lo) >= k,  count(bits >= hi) < k
    unsigned int lo = 0u, hi = 0x7f800000u;
    for (int it = 0; it < 32; ++it) {
        if (hi - lo <= 1u) break;                        // uniform across block
        const unsigned int mid = lo + ((hi - lo) >> 1);  // mid >= 1
        int c = 0;
#pragma unroll
        for (int i = 0; i < 2 * NPT2; ++i)
            c += (int)__popcll(__ballot(v[i] >= mid));   // wave-uniform count
        if ((threadIdx.x & 63) == 0) atomicAdd(&s_cnt[it], c);
        __syncthreads();                                 // the ONLY barrier per step
        const int cnt = s_cnt[it];
        if (cnt >= k) lo = mid; else hi = mid;
    }

    const unsigned int T = lo;           // exactly the k-th largest value's bits
#pragma unroll
    for (int i = 0; i < NPT2; ++i) {
        const int idx2 = threadIdx.x + i * K2_BLOCK;
        if (idx2 < V2_) {
            const unsigned int a = v[2 * i], c = v[2 * i + 1];
            float rx = 0.0f, ry = 0.0f;
            if (a >= T) rx = log1pf(__uint_as_float(a));
            if (c >= T) ry = log1pf(__uint_as_float(c));
            row2[idx2] = make_float2(rx, ry);
        }
    }
}

extern "C" void kernel_launch(void* const* d_in, const int* in_sizes, int n_in,
                              void* d_out, int out_size, void* d_ws, size_t ws_size,
                              hipStream_t stream) {
    const float* logits = (const float*)d_in[0];
    const int*   mask   = (const int*)d_in[1];
    const int*   topk   = (const int*)d_in[2];
    float*       out    = (float*)d_out;
    float*       ws     = (float*)d_ws;   // needs NS*B*V*4 = 15.6 MB of scratch

    dim3 g1(VSPLIT, NS, B_);
    splade_partial_max<<<g1, K1_THREADS, 0, stream>>>(logits, mask, ws);
    dim3 gm(KM_BLOCKS_X, B_);
    splade_merge<<<gm, KM_THREADS, 0, stream>>>(ws, out);
    splade_topk_kernel<<<B_, K2_BLOCK, 0, stream>>>(out, topk);
}